// Round 7
// baseline (32.366 us; speedup 1.0000x reference)
//
#include <hip/hip_runtime.h>

// GaussianSpot: out[k,b,i,j] = h/(2*pi*w^2) * exp(-0.5*((i-sx)^2+(j-sy)^2)/w^2)
// Separable: = [scale*exp2(c*(i-sx)^2)] * [exp2(c*(j-sy)^2)],  c = -0.5*log2(e)/w^2
// K=2, B=100000, D=14 -> 200000 spots x 196 px = 39.2M f32 (156.8 MB streamed write).
//
// R6: wave-autonomous, BARRIER-FREE structure. 16 spots per wave, 4 waves/block,
// no __syncthreads. Each wave stages params + 1D exp tables in a private LDS
// region and orders its own producer->consumer handoff with s_waitcnt lgkmcnt(0)
// (per-wave LDS counter; lanes are lockstep within a wave). 32 independent
// waves/CU hide each other's gather/exp latency under streaming stores
// continuously — removing the t=0 all-blocks-stalled prologue and both barriers.

typedef float f32x4 __attribute__((ext_vector_type(4)));

#define B_NUM   100000u
#define F_NUM   500
#define D_DIM   14u
#define SPW     16u              // spots per wave
#define WPB     4u               // waves per block (256 threads)
#define SPB     (SPW * WPB)      // 64 spots per block
#define NBLK    (200000 / SPB)   // 3125 blocks exactly
// Per-wave LDS region (floats):
//  [0,16) sx | [16,32) sy | [32,48) c | [48,64) scale | [64,320) ex | [320,576) ey
#define WREG    576u

__global__ __launch_bounds__(256) void gspot_kernel(
    const float* __restrict__ height,
    const float* __restrict__ width,
    const float* __restrict__ xoff,
    const float* __restrict__ yoff,
    const float* __restrict__ tlocs,   // [N, F, 2]
    const int*   __restrict__ n_idx,   // [B]
    const int*   __restrict__ f_idx,   // [B]
    f32x4*       __restrict__ out)
{
    __shared__ float lds[WPB * WREG];

    const float HALF_LOG2E = 0.7213475204444817f;   // 0.5 * log2(e)
    const float INV_2PI    = 0.15915494309189535f;  // 1 / (2*pi)

    const unsigned tid  = threadIdx.x;
    const unsigned wave = tid >> 6;
    const unsigned lane = tid & 63u;
    float* wl = &lds[wave * WREG];
    const unsigned wave_spot0 = blockIdx.x * SPB + wave * SPW;

    // ---- Stage A: 16 lanes resolve the gather chain for this wave's spots ----
    if (lane < SPW) {
        unsigned spot = wave_spot0 + lane;
        unsigned b    = spot >= B_NUM ? spot - B_NUM : spot;   // k*B+b layout, K=2
        float h  = height[spot];
        float w  = width[spot];
        float sx = xoff[spot];
        float sy = yoff[spot];
        int n = n_idx[b];
        int f = f_idx[b];
        const float* tl = tlocs + ((unsigned)(n * F_NUM + f)) * 2u;
        sx += tl[0];
        sy += tl[1];
        float inv = __builtin_amdgcn_rcpf(w * w);
        wl[lane]        = sx;
        wl[16u + lane]  = sy;
        wl[32u + lane]  = -HALF_LOG2E * inv;
        wl[48u + lane]  = h * inv * INV_2PI;
    }
    // Wave-private LDS handoff: drain this wave's ds_writes; no s_barrier needed.
    asm volatile("s_waitcnt lgkmcnt(0)" ::: "memory");
    __builtin_amdgcn_sched_barrier(0);

    // ---- Stage B: 16 spots * 28 1D exps = 448 items = 7 per lane exactly ----
    #pragma unroll
    for (unsigned k = 0; k < 7u; ++k) {
        unsigned item = lane + 64u * k;
        unsigned sp   = item / 28u;          // magic-mul
        unsigned r    = item - sp * 28u;
        float c = wl[32u + sp];
        if (r < D_DIM) {
            float d = (float)r - wl[sp];
            wl[64u + sp * 16u + r] = wl[48u + sp] * __builtin_amdgcn_exp2f(c * d * d);
        } else {
            unsigned j = r - D_DIM;
            float d = (float)j - wl[16u + sp];
            wl[320u + sp * 16u + j] = __builtin_amdgcn_exp2f(c * d * d);
        }
    }
    asm volatile("s_waitcnt lgkmcnt(0)" ::: "memory");
    __builtin_amdgcn_sched_barrier(0);

    // ---- Stage C: 16 spots * 49 f4 = 784 items = 12 full iters + 16 lanes ----
    f32x4* op = out + (size_t)wave_spot0 * 49u;
    #pragma unroll
    for (unsigned k = 0; k < 13u; ++k) {
        unsigned idx = lane + 64u * k;
        if (k < 12u || lane < 16u) {         // 784 = 12*64 + 16
            unsigned sp = idx / 49u;         // magic-mul
            unsigned q  = idx - sp * 49u;
            unsigned p0 = q * 4u;
            const float* exb = &wl[64u  + sp * 16u];
            const float* eyb = &wl[320u + sp * 16u];
            f32x4 e;
            #pragma unroll
            for (int m = 0; m < 4; ++m) {
                unsigned p = p0 + (unsigned)m;   // pixel 0..195
                unsigned i = p / D_DIM;          // magic-mul
                unsigned j = p - i * D_DIM;
                e[m] = exb[i] * eyb[j];
            }
            op[idx] = e;
        }
    }
}

extern "C" void kernel_launch(void* const* d_in, const int* in_sizes, int n_in,
                              void* d_out, int out_size, void* d_ws, size_t ws_size,
                              hipStream_t stream) {
    const float* height = (const float*)d_in[0];
    const float* width  = (const float*)d_in[1];
    const float* x      = (const float*)d_in[2];
    const float* y      = (const float*)d_in[3];
    const float* tlocs  = (const float*)d_in[4];
    const int*   n_idx  = (const int*)d_in[5];
    const int*   f_idx  = (const int*)d_in[6];
    f32x4* out = (f32x4*)d_out;

    hipLaunchKernelGGL(gspot_kernel, dim3(NBLK), dim3(256), 0, stream,
                       height, width, x, y, tlocs, n_idx, f_idx, out);
}